// Round 1
// baseline (812.141 us; speedup 1.0000x reference)
//
#include <hip/hip_runtime.h>

#define NROWS 8192
#define DIN   512
#define DATT  64
#define KTOP  16
#define PANEL 1024
#define NEG_INF (-3.0e38f)

typedef _Float16 f16x8 __attribute__((ext_vector_type(8)));
typedef float    fx4   __attribute__((ext_vector_type(4)));

// ---------------- small conversion kernels ----------------
__global__ void k_conv_f16(const float* __restrict__ in, _Float16* __restrict__ out, int n) {
    int i = blockIdx.x * 256 + threadIdx.x;
    if (i < n) out[i] = (_Float16)in[i];
}

// W13T[c][k] = sum_e W1[e][k] * W2[e][c]   (c<64, k<512), stored fp16
__global__ void k_w13t(const float* __restrict__ W1, const float* __restrict__ W2,
                       _Float16* __restrict__ W13T) {
    int id = blockIdx.x * 256 + threadIdx.x;   // 0..32767
    int c = id >> 9, k = id & 511;
    float acc = 0.f;
    #pragma unroll 8
    for (int e = 0; e < 64; e++) acc += W1[e*512 + k] * W2[e*64 + c];
    W13T[c*512 + k] = (_Float16)acc;
}

// ---------------- generic fp16 MFMA NT-GEMM ----------------
// C[i][j] = sum_k A[i*K+k]*B[j*K+k] (+bias[j]) (+C if ACCUM); out fp32 or fp16.
// block = WR*WC waves; wave tile (RM*16) x (RN*16).
template<int RM, int RN, int WR, int WC, bool OUTF16, bool ACCUM, bool BIAS>
__launch_bounds__(256)
__global__ void k_gemm_nt(const _Float16* __restrict__ A, const _Float16* __restrict__ B,
                          float* __restrict__ Cf, _Float16* __restrict__ Ch,
                          const float* __restrict__ bias, int M, int N, int K) {
    const int tid  = threadIdx.x;
    const int lane = tid & 63;
    const int wid  = tid >> 6;
    const int wr   = wid / WC;
    const int wc   = wid % WC;
    const int bm   = blockIdx.x * (WR*RM*16) + wr*(RM*16);
    const int bn   = blockIdx.y * (WC*RN*16) + wc*(RN*16);
    const int lr   = lane & 15;
    const int kg   = lane >> 4;

    fx4 acc[RM][RN];
    #pragma unroll
    for (int m = 0; m < RM; m++)
        #pragma unroll
        for (int n = 0; n < RN; n++)
            acc[m][n] = (fx4){0.f, 0.f, 0.f, 0.f};

    const _Float16* Ap = A + (size_t)(bm + lr) * K + kg*8;
    const _Float16* Bp = B + (size_t)(bn + lr) * K + kg*8;

    for (int k0 = 0; k0 < K; k0 += 32) {
        f16x8 af[RM], bf[RN];
        #pragma unroll
        for (int m = 0; m < RM; m++)
            af[m] = *(const f16x8*)(Ap + (size_t)m*16*K + k0);
        #pragma unroll
        for (int n = 0; n < RN; n++)
            bf[n] = *(const f16x8*)(Bp + (size_t)n*16*K + k0);
        #pragma unroll
        for (int m = 0; m < RM; m++)
            #pragma unroll
            for (int n = 0; n < RN; n++)
                acc[m][n] = __builtin_amdgcn_mfma_f32_16x16x32_f16(af[m], bf[n], acc[m][n], 0, 0, 0);
    }

    // C/D layout (m89-verified): col = lane&15, row = (lane>>4)*4 + r
    #pragma unroll
    for (int m = 0; m < RM; m++) {
        #pragma unroll
        for (int n = 0; n < RN; n++) {
            const int col = bn + n*16 + lr;
            const float bv = BIAS ? bias[col] : 0.f;
            #pragma unroll
            for (int r = 0; r < 4; r++) {
                const int row = bm + m*16 + kg*4 + r;
                const size_t off = (size_t)row * N + col;
                float v = acc[m][n][r] + bv;
                if (ACCUM) v += Cf[off];
                if (OUTF16) Ch[off] = (_Float16)v;
                else        Cf[off] = v;
            }
        }
    }
}

// ---------------- per-row top-16 + softmax ----------------
__launch_bounds__(256)
__global__ void k_topk_softmax(const float* __restrict__ S,
                               float* __restrict__ Pval, int* __restrict__ Pidx,
                               int row_off) {
    const int r = blockIdx.x;
    const float* srow = S + (size_t)r * NROWS;
    const int tid  = threadIdx.x;
    const int lane = tid & 63, w = tid >> 6;

    float v[KTOP]; int ix[KTOP];
    #pragma unroll
    for (int s = 0; s < KTOP; s++) { v[s] = NEG_INF; ix[s] = -1; }
    float vmin = NEG_INF;

    for (int j = tid; j < NROWS; j += 256) {
        float x = srow[j];
        if (x > vmin) {
            int slot = 0; float mn = v[0];
            #pragma unroll
            for (int s = 1; s < KTOP; s++) if (v[s] < mn) { mn = v[s]; slot = s; }
            #pragma unroll
            for (int s = 0; s < KTOP; s++) if (s == slot) { v[s] = x; ix[s] = j; }
            vmin = v[0];
            #pragma unroll
            for (int s = 1; s < KTOP; s++) vmin = fminf(vmin, v[s]);
        }
    }

    __shared__ float sv[4];   __shared__ int si[4];
    __shared__ float outv[KTOP]; __shared__ int outi[KTOP];

    for (int round = 0; round < KTOP; round++) {
        float lm = v[0]; int li = ix[0];
        #pragma unroll
        for (int s = 1; s < KTOP; s++)
            if (v[s] > lm || (v[s] == lm && ix[s] < li)) { lm = v[s]; li = ix[s]; }
        #pragma unroll
        for (int off = 32; off > 0; off >>= 1) {
            float ov = __shfl_down(lm, off);
            int   oi = __shfl_down(li, off);
            if (ov > lm || (ov == lm && oi < li)) { lm = ov; li = oi; }
        }
        if (lane == 0) { sv[w] = lm; si[w] = li; }
        __syncthreads();
        if (tid == 0) {
            float bmv = sv[0]; int bi = si[0];
            for (int q = 1; q < 4; q++)
                if (sv[q] > bmv || (sv[q] == bmv && si[q] < bi)) { bmv = sv[q]; bi = si[q]; }
            outv[round] = bmv; outi[round] = bi;
        }
        __syncthreads();
        const int bi = outi[round];
        #pragma unroll
        for (int s = 0; s < KTOP; s++)
            if (ix[s] == bi) v[s] = NEG_INF;
    }
    __syncthreads();

    if (tid < KTOP) {
        const float m = outv[0];                 // first extracted = row max
        const float e = __expf(outv[tid] - m);
        float ssum = e;
        #pragma unroll
        for (int off = 8; off > 0; off >>= 1) ssum += __shfl_down(ssum, off);
        ssum = __shfl(ssum, 0);
        const int ra = row_off + r;
        Pval[ra*KTOP + tid] = e / ssum;
        Pidx[ra*KTOP + tid] = outi[tid];
    }
}

// ---------------- sparse P @ H gather ----------------
template<bool WF32>
__launch_bounds__(256)
__global__ void k_gather(const float* __restrict__ Pval, const int* __restrict__ Pidx,
                         const float* __restrict__ Hin, float* __restrict__ Hf,
                         _Float16* __restrict__ Hh) {
    const int row = blockIdx.x, tid = threadIdx.x;
    __shared__ float pv[KTOP]; __shared__ int pi[KTOP];
    if (tid < KTOP) { pv[tid] = Pval[row*KTOP + tid]; pi[tid] = Pidx[row*KTOP + tid]; }
    __syncthreads();
    for (int c = tid; c < DIN; c += 256) {
        float acc = 0.f;
        #pragma unroll
        for (int t = 0; t < KTOP; t++) acc += pv[t] * Hin[(size_t)pi[t]*DIN + c];
        if (WF32) Hf[(size_t)row*DIN + c] = acc;
        Hh[(size_t)row*DIN + c] = (_Float16)acc;
    }
}

// ---------------- residual + LayerNorm ----------------
__launch_bounds__(256)
__global__ void k_ln(const float* __restrict__ X, const float* __restrict__ Z,
                     const float* __restrict__ gamma, const float* __restrict__ beta,
                     float* __restrict__ out) {
    const int row = blockIdx.x, tid = threadIdx.x;
    const size_t base = (size_t)row * DIN;
    float y0 = X[base + tid]       + Z[base + tid];
    float y1 = X[base + tid + 256] + Z[base + tid + 256];
    float s  = y0 + y1;
    float s2 = y0*y0 + y1*y1;
    #pragma unroll
    for (int off = 32; off > 0; off >>= 1) {
        s  += __shfl_down(s,  off);
        s2 += __shfl_down(s2, off);
    }
    __shared__ float as_[4], as2_[4], mv[2];
    const int lane = tid & 63, w = tid >> 6;
    if (lane == 0) { as_[w] = s; as2_[w] = s2; }
    __syncthreads();
    if (tid == 0) {
        float ts = as_[0] + as_[1] + as_[2] + as_[3];
        float t2 = as2_[0] + as2_[1] + as2_[2] + as2_[3];
        float mu  = ts / 512.f;
        float var = t2 / 512.f - mu*mu;
        mv[0] = mu; mv[1] = rsqrtf(var + 1e-5f);
    }
    __syncthreads();
    const float mu = mv[0], rs = mv[1];
    out[base + tid]       = (y0 - mu) * rs * gamma[tid]       + beta[tid];
    out[base + tid + 256] = (y1 - mu) * rs * gamma[tid + 256] + beta[tid + 256];
}

// ---------------- launcher ----------------
extern "C" void kernel_launch(void* const* d_in, const int* in_sizes, int n_in,
                              void* d_out, int out_size, void* d_ws, size_t ws_size,
                              hipStream_t stream) {
    const float* X     = (const float*)d_in[0];
    const float* W1    = (const float*)d_in[1];
    const float* W2    = (const float*)d_in[2];
    const float* W3    = (const float*)d_in[3];
    const float* mixW  = (const float*)d_in[4];
    const float* mixB  = (const float*)d_in[5];
    const float* gamma = (const float*)d_in[6];
    const float* beta  = (const float*)d_in[7];
    float* out = (float*)d_out;

    char* ws = (char*)d_ws;
    size_t off = 0;
    auto alloc = [&](size_t bytes) {
        void* p = ws + off;
        off += (bytes + 255) & ~(size_t)255;
        return p;
    };
    _Float16* Xh   = (_Float16*)alloc((size_t)NROWS*DIN*2);
    _Float16* Ah   = (_Float16*)alloc((size_t)NROWS*DATT*2);
    _Float16* Kh   = (_Float16*)alloc((size_t)NROWS*DATT*2);
    _Float16* W13T = (_Float16*)alloc((size_t)DATT*DIN*2);
    _Float16* W3h  = (_Float16*)alloc((size_t)DATT*DIN*2);
    _Float16* mWh  = (_Float16*)alloc((size_t)2*DIN*DIN*2);
    float*    Pval = (float*)alloc((size_t)NROWS*KTOP*4);
    int*      Pidx = (int*)alloc((size_t)NROWS*KTOP*4);
    float*    H1f  = (float*)alloc((size_t)NROWS*DIN*4);
    _Float16* H1h  = (_Float16*)alloc((size_t)NROWS*DIN*2);
    _Float16* H2h  = (_Float16*)alloc((size_t)NROWS*DIN*2);
    float*    Zacc = (float*)alloc((size_t)NROWS*DIN*4);
    float*    Sp   = (float*)alloc((size_t)PANEL*NROWS*4);
    (void)ws_size; (void)in_sizes; (void)n_in; (void)out_size;

    dim3 b256(256);

    // dtype conversions + W13T = W1.T@W2 (transposed, fp16)
    k_conv_f16<<<dim3((NROWS*DIN + 255)/256), b256, 0, stream>>>(X, Xh, NROWS*DIN);
    k_conv_f16<<<dim3((DATT*DIN + 255)/256),  b256, 0, stream>>>(W3, W3h, DATT*DIN);
    k_conv_f16<<<dim3((2*DIN*DIN + 255)/256), b256, 0, stream>>>(mixW, mWh, 2*DIN*DIN);
    k_w13t<<<dim3(DATT*DIN/256), b256, 0, stream>>>(W1, W2, W13T);

    // A = X@ (W1.T@W2)  [8192,64] fp16 ;  Km = X@W3.T [8192,64] fp16
    k_gemm_nt<2,4,4,1,true,false,false><<<dim3(NROWS/128, 1), b256, 0, stream>>>(
        Xh, W13T, nullptr, Ah, nullptr, NROWS, DATT, DIN);
    k_gemm_nt<2,4,4,1,true,false,false><<<dim3(NROWS/128, 1), b256, 0, stream>>>(
        Xh, W3h, nullptr, Kh, nullptr, NROWS, DATT, DIN);

    // S panels (1024 rows each): GEMM -> top-16 + softmax (panel stays L3-resident)
    for (int p = 0; p < NROWS/PANEL; p++) {
        k_gemm_nt<4,4,2,2,false,false,false><<<dim3(PANEL/128, NROWS/128), b256, 0, stream>>>(
            Ah + (size_t)p*PANEL*DATT, Kh, Sp, nullptr, nullptr, PANEL, NROWS, DATT);
        k_topk_softmax<<<dim3(PANEL), b256, 0, stream>>>(Sp, Pval, Pidx, p*PANEL);
    }

    // H1 = P@X
    k_gather<true><<<dim3(NROWS), b256, 0, stream>>>(Pval, Pidx, X, H1f, H1h);
    // Zacc = H1@mixW0.T + mixB0
    k_gemm_nt<4,4,2,2,false,false,true><<<dim3(NROWS/128, DIN/128), b256, 0, stream>>>(
        H1h, mWh, Zacc, nullptr, mixB, NROWS, DIN, DIN);
    // H2 = P@H1
    k_gather<false><<<dim3(NROWS), b256, 0, stream>>>(Pval, Pidx, H1f, nullptr, H2h);
    // Zacc += H2@mixW1.T + mixB1
    k_gemm_nt<4,4,2,2,false,true,true><<<dim3(NROWS/128, DIN/128), b256, 0, stream>>>(
        H2h, mWh + (size_t)DIN*DIN, Zacc, nullptr, mixB + DIN, NROWS, DIN, DIN);
    // out = LN(X + Zacc)*gamma + beta
    k_ln<<<dim3(NROWS), b256, 0, stream>>>(X, Zacc, gamma, beta, out);
}

// Round 3
// 435.664 us; speedup vs baseline: 1.8641x; 1.8641x over previous
//
#include <hip/hip_runtime.h>

#define NROWS 8192
#define DIN   512
#define DATT  64
#define KTOP  16
#define PANEL 1024
#define CMAX  128
#define NEG_INF (-3.0e38f)

typedef _Float16 f16x8 __attribute__((ext_vector_type(8)));
typedef float    fx4   __attribute__((ext_vector_type(4)));

// ---------------- conversion / split kernels ----------------
__global__ void k_conv_f16(const float* __restrict__ in, _Float16* __restrict__ out, int n) {
    int i = blockIdx.x * 256 + threadIdx.x;
    if (i < n) out[i] = (_Float16)in[i];
}

// fp32 -> (hi fp16, lo fp16) split: x = hi + lo + O(x*2^-22)
__global__ void k_split(const float* __restrict__ in, _Float16* __restrict__ hi,
                        _Float16* __restrict__ lo, int n) {
    int i = blockIdx.x * 256 + threadIdx.x;
    if (i < n) {
        float x = in[i];
        _Float16 h = (_Float16)x;
        hi[i] = h;
        lo[i] = (_Float16)(x - (float)h);
    }
}

// Wcat fp32 [128][512]: rows 0..63 = Σ_e W1[e][k]*W2[e][c] ; rows 64..127 = W3
__global__ void k_wcat(const float* __restrict__ W1, const float* __restrict__ W2,
                       const float* __restrict__ W3, float* __restrict__ Wcat) {
    int id = blockIdx.x * 256 + threadIdx.x;   // 0..65535
    int c = id >> 9, k = id & 511;
    float r;
    if (c < 64) {
        float acc = 0.f;
        #pragma unroll 8
        for (int e = 0; e < 64; e++) acc += W1[e*512 + k] * W2[e*64 + c];
        r = acc;
    } else {
        r = W3[(c - 64)*512 + k];
    }
    Wcat[c*512 + k] = r;
}

// ---------------- projection: Af32 = X @ Wcat.T (3-term split-fp16 MFMA) ----------------
// M=NROWS, N=128, K=DIN. Block: 4 waves, 128x64 tile. Writes fp32 AND fp16 copies.
__launch_bounds__(256)
__global__ void k_proj(const _Float16* __restrict__ Ahi, const _Float16* __restrict__ Alo,
                       const _Float16* __restrict__ Bhi, const _Float16* __restrict__ Blo,
                       float* __restrict__ Cf, _Float16* __restrict__ Ch) {
    const int tid = threadIdx.x, lane = tid & 63, wid = tid >> 6;
    const int bm = blockIdx.x * 128 + wid * 32;   // RM=2 -> 32 rows/wave
    const int bn = blockIdx.y * 64;               // RN=4 -> 64 cols
    const int lr = lane & 15, kg = lane >> 4;

    fx4 acc[2][4];
    #pragma unroll
    for (int m = 0; m < 2; m++)
        #pragma unroll
        for (int n = 0; n < 4; n++) acc[m][n] = (fx4){0.f,0.f,0.f,0.f};

    const _Float16* Aph = Ahi + (size_t)(bm + lr) * DIN + kg*8;
    const _Float16* Apl = Alo + (size_t)(bm + lr) * DIN + kg*8;
    const _Float16* Bph = Bhi + (size_t)(bn + lr) * DIN + kg*8;
    const _Float16* Bpl = Blo + (size_t)(bn + lr) * DIN + kg*8;

    for (int k0 = 0; k0 < DIN; k0 += 32) {
        f16x8 ah[2], al[2], bh[4], bl[4];
        #pragma unroll
        for (int m = 0; m < 2; m++) {
            ah[m] = *(const f16x8*)(Aph + (size_t)m*16*DIN + k0);
            al[m] = *(const f16x8*)(Apl + (size_t)m*16*DIN + k0);
        }
        #pragma unroll
        for (int n = 0; n < 4; n++) {
            bh[n] = *(const f16x8*)(Bph + (size_t)n*16*DIN + k0);
            bl[n] = *(const f16x8*)(Bpl + (size_t)n*16*DIN + k0);
        }
        #pragma unroll
        for (int m = 0; m < 2; m++)
            #pragma unroll
            for (int n = 0; n < 4; n++) {
                acc[m][n] = __builtin_amdgcn_mfma_f32_16x16x32_f16(ah[m], bh[n], acc[m][n], 0,0,0);
                acc[m][n] = __builtin_amdgcn_mfma_f32_16x16x32_f16(ah[m], bl[n], acc[m][n], 0,0,0);
                acc[m][n] = __builtin_amdgcn_mfma_f32_16x16x32_f16(al[m], bh[n], acc[m][n], 0,0,0);
            }
    }

    #pragma unroll
    for (int m = 0; m < 2; m++)
        #pragma unroll
        for (int n = 0; n < 4; n++) {
            const int col = bn + n*16 + lr;
            #pragma unroll
            for (int r = 0; r < 4; r++) {
                const int row = bm + m*16 + kg*4 + r;
                const size_t off = (size_t)row * 128 + col;
                float v = acc[m][n][r];
                Cf[off] = v;
                Ch[off] = (_Float16)v;
            }
        }
}

// ---------------- generic fp16 MFMA NT-GEMM (strided) ----------------
template<int RM, int RN, int WR, int WC, bool OUTF16, bool ACCUM, bool BIAS>
__launch_bounds__(256)
__global__ void k_gemm_nt(const _Float16* __restrict__ A, const _Float16* __restrict__ B,
                          float* __restrict__ Cf, _Float16* __restrict__ Ch,
                          const float* __restrict__ bias, int M, int N, int K,
                          int lda, int ldb) {
    const int tid  = threadIdx.x;
    const int lane = tid & 63;
    const int wid  = tid >> 6;
    const int wr   = wid / WC;
    const int wc   = wid % WC;
    const int bm   = blockIdx.x * (WR*RM*16) + wr*(RM*16);
    const int bn   = blockIdx.y * (WC*RN*16) + wc*(RN*16);
    const int lr   = lane & 15;
    const int kg   = lane >> 4;

    fx4 acc[RM][RN];
    #pragma unroll
    for (int m = 0; m < RM; m++)
        #pragma unroll
        for (int n = 0; n < RN; n++)
            acc[m][n] = (fx4){0.f, 0.f, 0.f, 0.f};

    const _Float16* Ap = A + (size_t)(bm + lr) * lda + kg*8;
    const _Float16* Bp = B + (size_t)(bn + lr) * ldb + kg*8;

    for (int k0 = 0; k0 < K; k0 += 32) {
        f16x8 af[RM], bf[RN];
        #pragma unroll
        for (int m = 0; m < RM; m++)
            af[m] = *(const f16x8*)(Ap + (size_t)m*16*lda + k0);
        #pragma unroll
        for (int n = 0; n < RN; n++)
            bf[n] = *(const f16x8*)(Bp + (size_t)n*16*ldb + k0);
        #pragma unroll
        for (int m = 0; m < RM; m++)
            #pragma unroll
            for (int n = 0; n < RN; n++)
                acc[m][n] = __builtin_amdgcn_mfma_f32_16x16x32_f16(af[m], bf[n], acc[m][n], 0, 0, 0);
    }

    #pragma unroll
    for (int m = 0; m < RM; m++) {
        #pragma unroll
        for (int n = 0; n < RN; n++) {
            const int col = bn + n*16 + lr;
            const float bv = BIAS ? bias[col] : 0.f;
            #pragma unroll
            for (int r = 0; r < 4; r++) {
                const int row = bm + m*16 + kg*4 + r;
                const size_t off = (size_t)row * N + col;
                float v = acc[m][n][r] + bv;
                if (ACCUM) v += Cf[off];
                if (OUTF16) Ch[off] = (_Float16)v;
                else        Cf[off] = v;
            }
        }
    }
}

// ---------------- per-row candidate prefilter (threshold + gather, NO extraction) ----------------
__launch_bounds__(256)
__global__ void k_topk_cand(const _Float16* __restrict__ S, int* __restrict__ CandIdx,
                            int* __restrict__ CandCnt, int row_off) {
    const int r = blockIdx.x;
    const _Float16* srow = S + (size_t)r * NROWS;
    const int tid = threadIdx.x;
    const int lane = tid & 63, w = tid >> 6;

    float v[32];
    #pragma unroll
    for (int i = 0; i < 4; i++) {
        f16x8 h = *(const f16x8*)(srow + i*2048 + tid*8);
        #pragma unroll
        for (int j = 0; j < 8; j++) v[i*8 + j] = (float)h[j];
    }

    float sm = 0.f, s2 = 0.f;
    #pragma unroll
    for (int i = 0; i < 32; i++) { sm += v[i]; s2 += v[i]*v[i]; }
    #pragma unroll
    for (int off = 32; off > 0; off >>= 1) {
        sm += __shfl_down(sm, off);
        s2 += __shfl_down(s2, off);
    }
    __shared__ float redf[4][2];
    __shared__ int   redi[4];
    __shared__ float s_t;
    __shared__ int   s_done;
    if (lane == 0) { redf[w][0] = sm; redf[w][1] = s2; }
    if (tid == 0) s_done = 0;
    __syncthreads();
    float sigma_reg = 0.f;
    if (tid == 0) {
        float tsm = redf[0][0] + redf[1][0] + redf[2][0] + redf[3][0];
        float ts2 = redf[0][1] + redf[1][1] + redf[2][1] + redf[3][1];
        float mu  = tsm / (float)NROWS;
        float var = ts2 / (float)NROWS - mu*mu;
        float sg  = sqrtf(fmaxf(var, 0.f));
        if (sg < 1e-5f) sg = 1e-5f;
        sigma_reg = sg;
        s_t = mu + 2.55f * sg;     // expected ~44 survivors for Gaussian rows
    }
    __syncthreads();

    float tl = 0.f, th = 0.f; int have_tl = 0, have_th = 0;
    float step = 0.9f * sigma_reg;
    float t = s_t;
    for (int it = 0; it < 20; it++) {
        t = s_t;
        if (s_done) break;
        int c = 0;
        #pragma unroll
        for (int i = 0; i < 32; i++) c += (v[i] > t);
        #pragma unroll
        for (int off = 32; off > 0; off >>= 1) c += __shfl_down(c, off);
        if (lane == 0) redi[w] = c;
        __syncthreads();
        if (tid == 0) {
            int tot = redi[0] + redi[1] + redi[2] + redi[3];
            if (tot >= 24 && tot <= 112) {
                s_done = 1;
            } else if (tot < 24) {
                th = t; have_th = 1;
                s_t = have_tl ? 0.5f*(t + tl) : t - step;
                step *= 2.f;
            } else {
                tl = t; have_tl = 1;
                s_t = have_th ? 0.5f*(t + th) : t + step;
                step *= 2.f;
            }
        }
        __syncthreads();
    }
    t = s_t;

    __shared__ int s_n;
    if (tid == 0) s_n = 0;
    __syncthreads();
    int* crow = CandIdx + (size_t)(row_off + r) * CMAX;
    #pragma unroll
    for (int i = 0; i < 32; i++) {
        if (v[i] > t) {
            int p = atomicAdd(&s_n, 1);
            if (p < CMAX) crow[p] = (i >> 3)*2048 + tid*8 + (i & 7);
        }
    }
    __syncthreads();
    if (tid == 0) CandCnt[row_off + r] = min(s_n, CMAX);
}

// ---------------- fp32 rescore + exact top-16 + softmax ----------------
// 1 wave per row, 4 rows/block. Candidates rescored vs Af32 (L2/L3-resident).
__launch_bounds__(256)
__global__ void k_sel(const float* __restrict__ AK, const int* __restrict__ CandIdx,
                      const int* __restrict__ CandCnt,
                      float* __restrict__ Pval, int* __restrict__ Pidx) {
    const int row  = blockIdx.x*4 + (threadIdx.x >> 6);
    const int lane = threadIdx.x & 63;
    const int cnt  = CandCnt[row];
    const fx4* a4  = (const fx4*)(AK + (size_t)row * 128);

    float sv[2]; int si[2];
    #pragma unroll
    for (int q = 0; q < 2; q++) {
        const int c = lane + q*64;
        if (c < cnt) {
            const int idx = CandIdx[(size_t)row * CMAX + c];
            const fx4* k4 = (const fx4*)(AK + (size_t)idx * 128 + 64);
            float s = 0.f;
            #pragma unroll
            for (int d = 0; d < 16; d++) {
                fx4 av = a4[d], kv = k4[d];
                s += av[0]*kv[0] + av[1]*kv[1] + av[2]*kv[2] + av[3]*kv[3];
            }
            sv[q] = s; si[q] = idx;
        } else { sv[q] = NEG_INF; si[q] = 0x7fffffff; }
    }

    float m0 = 0.f, Z = 0.f, myv = NEG_INF; int myi = 0;
    for (int round = 0; round < KTOP; round++) {
        float bm = sv[0]; int bi = si[0];
        if (sv[1] > bm || (sv[1] == bm && si[1] < bi)) { bm = sv[1]; bi = si[1]; }
        #pragma unroll
        for (int off = 1; off < 64; off <<= 1) {
            float ov = __shfl_xor(bm, off);
            int   oi = __shfl_xor(bi, off);
            if (ov > bm || (ov == bm && oi < bi)) { bm = ov; bi = oi; }
        }
        if (round == 0) m0 = bm;
        Z += (bi == 0x7fffffff) ? 0.f : __expf(bm - m0);
        if (lane == round) { myv = bm; myi = bi; }
        #pragma unroll
        for (int q = 0; q < 2; q++)
            if (si[q] == bi) sv[q] = NEG_INF;
    }

    if (lane < KTOP) {
        const int oi = (myi >= 0 && myi < NROWS) ? myi : 0;
        const float e = (myi >= 0 && myi < NROWS) ? __expf(myv - m0) : 0.f;
        Pval[(size_t)row*KTOP + lane] = e / Z;
        Pidx[(size_t)row*KTOP + lane] = oi;
    }
}

// ---------------- sparse P @ H gather ----------------
template<bool WF32>
__launch_bounds__(256)
__global__ void k_gather(const float* __restrict__ Pval, const int* __restrict__ Pidx,
                         const float* __restrict__ Hin, float* __restrict__ Hf,
                         _Float16* __restrict__ Hh) {
    const int row = blockIdx.x, tid = threadIdx.x;
    __shared__ float pv[KTOP]; __shared__ int pi[KTOP];
    if (tid < KTOP) { pv[tid] = Pval[row*KTOP + tid]; pi[tid] = Pidx[row*KTOP + tid]; }
    __syncthreads();
    for (int c = tid; c < DIN; c += 256) {
        float acc = 0.f;
        #pragma unroll
        for (int t = 0; t < KTOP; t++) acc += pv[t] * Hin[(size_t)pi[t]*DIN + c];
        if (WF32) Hf[(size_t)row*DIN + c] = acc;
        Hh[(size_t)row*DIN + c] = (_Float16)acc;
    }
}

// ---------------- residual + LayerNorm ----------------
__launch_bounds__(256)
__global__ void k_ln(const float* __restrict__ X, const float* __restrict__ Z,
                     const float* __restrict__ gamma, const float* __restrict__ beta,
                     float* __restrict__ out) {
    const int row = blockIdx.x, tid = threadIdx.x;
    const size_t base = (size_t)row * DIN;
    float y0 = X[base + tid]       + Z[base + tid];
    float y1 = X[base + tid + 256] + Z[base + tid + 256];
    float s  = y0 + y1;
    float s2 = y0*y0 + y1*y1;
    #pragma unroll
    for (int off = 32; off > 0; off >>= 1) {
        s  += __shfl_down(s,  off);
        s2 += __shfl_down(s2, off);
    }
    __shared__ float as_[4], as2_[4], mv[2];
    const int lane = tid & 63, w = tid >> 6;
    if (lane == 0) { as_[w] = s; as2_[w] = s2; }
    __syncthreads();
    if (tid == 0) {
        float ts = as_[0] + as_[1] + as_[2] + as_[3];
        float t2 = as2_[0] + as2_[1] + as2_[2] + as2_[3];
        float mu  = ts / 512.f;
        float var = t2 / 512.f - mu*mu;
        mv[0] = mu; mv[1] = rsqrtf(var + 1e-5f);
    }
    __syncthreads();
    const float mu = mv[0], rs = mv[1];
    out[base + tid]       = (y0 - mu) * rs * gamma[tid]       + beta[tid];
    out[base + tid + 256] = (y1 - mu) * rs * gamma[tid + 256] + beta[tid + 256];
}

// ---------------- launcher ----------------
extern "C" void kernel_launch(void* const* d_in, const int* in_sizes, int n_in,
                              void* d_out, int out_size, void* d_ws, size_t ws_size,
                              hipStream_t stream) {
    const float* X     = (const float*)d_in[0];
    const float* W1    = (const float*)d_in[1];
    const float* W2    = (const float*)d_in[2];
    const float* W3    = (const float*)d_in[3];
    const float* mixW  = (const float*)d_in[4];
    const float* mixB  = (const float*)d_in[5];
    const float* gamma = (const float*)d_in[6];
    const float* beta  = (const float*)d_in[7];
    float* out = (float*)d_out;

    char* ws = (char*)d_ws;
    size_t off = 0;
    auto alloc = [&](size_t bytes) {
        void* p = ws + off;
        off += (bytes + 255) & ~(size_t)255;
        return p;
    };
    _Float16* Xhi  = (_Float16*)alloc((size_t)NROWS*DIN*2);
    _Float16* Xlo  = (_Float16*)alloc((size_t)NROWS*DIN*2);
    float*    Wcat = (float*)alloc((size_t)128*DIN*4);
    _Float16* Whi  = (_Float16*)alloc((size_t)128*DIN*2);
    _Float16* Wlo  = (_Float16*)alloc((size_t)128*DIN*2);
    float*    Af32 = (float*)alloc((size_t)NROWS*128*4);
    _Float16* AKh  = (_Float16*)alloc((size_t)NROWS*128*2);
    _Float16* mWh  = (_Float16*)alloc((size_t)2*DIN*DIN*2);
    float*    Pval = (float*)alloc((size_t)NROWS*KTOP*4);
    int*      Pidx = (int*)alloc((size_t)NROWS*KTOP*4);
    int*      CandIdx = (int*)alloc((size_t)NROWS*CMAX*4);
    int*      CandCnt = (int*)alloc((size_t)NROWS*4);
    float*    H1f  = (float*)alloc((size_t)NROWS*DIN*4);
    _Float16* H1h  = (_Float16*)alloc((size_t)NROWS*DIN*2);
    _Float16* H2h  = (_Float16*)alloc((size_t)NROWS*DIN*2);
    float*    Zacc = (float*)alloc((size_t)NROWS*DIN*4);
    _Float16* Sh   = (_Float16*)alloc((size_t)PANEL*NROWS*2);
    (void)ws_size; (void)in_sizes; (void)n_in; (void)out_size;

    dim3 b256(256);

    // prep: splits, Wcat, conversions
    k_split<<<dim3(NROWS*DIN/256), b256, 0, stream>>>(X, Xhi, Xlo, NROWS*DIN);
    k_wcat<<<dim3(128*DIN/256), b256, 0, stream>>>(W1, W2, W3, Wcat);
    k_split<<<dim3(128*DIN/256), b256, 0, stream>>>(Wcat, Whi, Wlo, 128*DIN);
    k_conv_f16<<<dim3(2*DIN*DIN/256), b256, 0, stream>>>(mixW, mWh, 2*DIN*DIN);

    // Af32 (fp32-grade) + AKh (fp16 copy) = X @ Wcat.T via one fused 3-term kernel
    k_proj<<<dim3(NROWS/128, 2), b256, 0, stream>>>(Xhi, Xlo, Whi, Wlo, Af32, AKh);

    // S panels (fp16, prefilter only): GEMM -> candidate gather
    for (int p = 0; p < NROWS/PANEL; p++) {
        k_gemm_nt<2,4,2,2,true,false,false><<<dim3(PANEL/64, NROWS/128), b256, 0, stream>>>(
            AKh + (size_t)p*PANEL*128, AKh + 64, nullptr, Sh, nullptr,
            PANEL, NROWS, DATT, 128, 128);
        k_topk_cand<<<dim3(PANEL), b256, 0, stream>>>(Sh, CandIdx, CandCnt, p*PANEL);
    }

    // fp32 rescore of candidates -> exact top-16 + softmax
    k_sel<<<dim3(NROWS/4), b256, 0, stream>>>(Af32, CandIdx, CandCnt, Pval, Pidx);

    // H1 = P@X ; Zacc = H1@mixW0.T + mixB0
    k_gather<true><<<dim3(NROWS), b256, 0, stream>>>(Pval, Pidx, X, H1f, H1h);
    k_gemm_nt<4,4,2,2,false,false,true><<<dim3(NROWS/128, DIN/128), b256, 0, stream>>>(
        H1h, mWh, Zacc, nullptr, mixB, NROWS, DIN, DIN, DIN, DIN);
    // H2 = P@H1 ; Zacc += H2@mixW1.T + mixB1
    k_gather<false><<<dim3(NROWS), b256, 0, stream>>>(Pval, Pidx, H1f, nullptr, H2h);
    k_gemm_nt<4,4,2,2,false,true,true><<<dim3(NROWS/128, DIN/128), b256, 0, stream>>>(
        H2h, mWh + (size_t)DIN*DIN, Zacc, nullptr, mixB + DIN, NROWS, DIN, DIN, DIN, DIN);
    // out = LN(X + Zacc)*gamma + beta
    k_ln<<<dim3(NROWS), b256, 0, stream>>>(X, Zacc, gamma, beta, out);
}